// Round 1
// baseline (4785.550 us; speedup 1.0000x reference)
//
#include <hip/hip_runtime.h>
#include <hip/hip_fp16.h>

// RNN scan: x_{t+1} = 0.9 x_t + 0.1 tanh(W x_t + Bs s_t + pad(u_t) + b)
// Persistent clustered kernel: 16 clusters x 16 WGs; W in registers (f16 hi/lo
// split, 3-MFMA compensated product ~f32 precision); x exchange via d_out +
// agent-scope flag counters in d_ws. Readout y = x @ Wy^T as separate GEMM.

#define DIMX 1024
#define DIMS 64
#define DIMY 256
#define TSTEPS 256
#define KEXT 1088   // 1024 + 64 (Bs columns folded into K)

typedef _Float16 f16x8 __attribute__((ext_vector_type(8)));
typedef _Float16 f16x4 __attribute__((ext_vector_type(4)));
typedef float f32x4 __attribute__((ext_vector_type(4)));
typedef float vf4 __attribute__((ext_vector_type(4)));

// LDS layout (dynamic, 95488 B):
//  Ahi : [34][16][40] f16   43520 B   (rows padded to 40 f16 = 80 B, 16B-aligned)
//  Alo : [34][16][40] f16   43520 B
//  red : [4][16][17] f32     4352 B   (k1->k0 partial-acc exchange)
//  ust : [16][64] f32        4096 B   (u staging, cluster-WG 0 only)
#define SCAN_LDS 95488

__global__ __launch_bounds__(512, 2) void scan_kernel(
    const float* __restrict__ x0, const float* __restrict__ ss,
    const float* __restrict__ us, const float* __restrict__ Bsm,
    const float* __restrict__ Wm, const float* __restrict__ bv,
    float* __restrict__ xs, unsigned* __restrict__ flags)
{
  extern __shared__ char smem[];
  _Float16* Ahi = (_Float16*)smem;
  _Float16* Alo = (_Float16*)(smem + 43520);
  float* red = (float*)(smem + 87040);
  float* ust = (float*)(smem + 91392);

  const int tid  = threadIdx.x;
  const int lane = tid & 63;
  const int wave = tid >> 6;        // 0..7
  const int n    = wave & 3;        // N-tile (16 cols) within WG
  const int kh   = wave >> 2;       // K-half (0: ksteps 0..16, 1: 17..33)
  const int bid  = blockIdx.x;
  // cluster decomposition: members of cluster c share bid%8 (XCD locality hint)
  const int jb   = bid >> 3;
  const int c    = (bid & 7) + 8 * (jb >> 4);   // 0..15
  const int s    = jb & 15;                     // WG within cluster
  const int row0 = c * 16;                      // batch rows of cluster
  const int col0 = s * 64;                      // output cols of WG
  unsigned* flag = flags + c * 32;              // 128B-padded counters

  const int l15 = lane & 15;
  const int lg  = lane >> 4;                    // 0..3
  const int jcol = col0 + n * 16 + l15;         // this lane's output column

  // ---- preload W slice (f16 hi/lo) into registers: 17 ksteps x 8 elems ----
  f16x8 Whi[17], Wlo[17];
#pragma unroll
  for (int i = 0; i < 17; ++i) {
    int g = kh * 17 + i;
    int kb = 32 * g + 8 * lg;
    vf4 v0, v1;
    if (g < 32) {
      const float* p = Wm + (size_t)jcol * 1024 + kb;
      v0 = *(const vf4*)p; v1 = *(const vf4*)(p + 4);
    } else {
      const float* p = Bsm + (size_t)jcol * 64 + (kb - 1024);
      v0 = *(const vf4*)p; v1 = *(const vf4*)(p + 4);
    }
#pragma unroll
    for (int e = 0; e < 4; ++e) {
      float va = v0[e]; _Float16 h = (_Float16)va;
      Whi[i][e] = h; Wlo[i][e] = (_Float16)(va - (float)h);
      float vb = v1[e]; _Float16 h2 = (_Float16)vb;
      Whi[i][e + 4] = h2; Wlo[i][e + 4] = (_Float16)(vb - (float)h2);
    }
  }

  const float bcol = bv[jcol];

  // x_old tile lives in k0-waves' registers (C/D layout: col=l15, row=lg*4+i)
  f32x4 xold = {0.f, 0.f, 0.f, 0.f};
  if (kh == 0) {
#pragma unroll
    for (int i = 0; i < 4; ++i)
      xold[i] = x0[(size_t)(row0 + lg * 4 + i) * 1024 + jcol];
  }

  // ---- init: x_seq[:,0,:] = x0 (this WG's tile) ----
  for (int idx = tid; idx < 1024; idx += 512) {
    int r = idx >> 6, cc = idx & 63;
    xs[((size_t)(row0 + r) * TSTEPS + 0) * 1024 + col0 + cc] =
        x0[(size_t)(row0 + r) * 1024 + col0 + cc];
  }
  __syncthreads();
  if (tid == 0)
    __hip_atomic_fetch_add(flag, 1u, __ATOMIC_RELEASE, __HIP_MEMORY_SCOPE_AGENT);

  const int srow = tid >> 5;   // stageA: row 0..15
  const int skk  = tid & 31;   // stageA: k 0..31
  const int tid2 = tid - 256;  // stageB threads (waves 4..7)

  for (int t = 0; t < TSTEPS - 1; ++t) {
    // ---- wait for all producers of x_t ----
    if (tid == 0) {
      unsigned tgt = 16u * (unsigned)(t + 1);
      while (__hip_atomic_load(flag, __ATOMIC_RELAXED, __HIP_MEMORY_SCOPE_AGENT) < tgt)
        __builtin_amdgcn_s_sleep(2);
      (void)__hip_atomic_load(flag, __ATOMIC_ACQUIRE, __HIP_MEMORY_SCOPE_AGENT);
    }
    __syncthreads();  // bar1

    // ---- stage A (ksteps 0..16, all k<544 -> x_seq), all 512 threads ----
    {
      const size_t bt = ((size_t)(row0 + srow) * TSTEPS + t) * 1024;
#pragma unroll
      for (int g = 0; g < 17; ++g) {
        float v = xs[bt + 32 * g + skk];
        _Float16 h = (_Float16)v;
        int a = (g * 16 + srow) * 40 + skk;
        Ahi[a] = h; Alo[a] = (_Float16)(v - (float)h);
      }
      if (s == 0) {
#pragma unroll
        for (int p = 0; p < 2; ++p) {
          int idx = tid + 512 * p;
          int ur = idx >> 6, uc = idx & 63;
          ust[idx] = us[((size_t)(row0 + ur) * TSTEPS + t) * 64 + uc];
        }
      }
    }
    __syncthreads();  // bar2

    f32x4 acc = {0.f, 0.f, 0.f, 0.f};
    if (kh == 0) {
      // ---- k0 waves: MFMA over ksteps 0..16 ----
#pragma unroll
      for (int i = 0; i < 17; ++i) {
        const _Float16* ap = Ahi + (i * 16 + l15) * 40 + 8 * lg;
        const _Float16* lp = Alo + (i * 16 + l15) * 40 + 8 * lg;
        f16x8 ah = *(const f16x8*)ap;
        f16x8 al = *(const f16x8*)lp;
        acc = __builtin_amdgcn_mfma_f32_16x16x32_f16(ah, Whi[i], acc, 0, 0, 0);
        acc = __builtin_amdgcn_mfma_f32_16x16x32_f16(ah, Wlo[i], acc, 0, 0, 0);
        acc = __builtin_amdgcn_mfma_f32_16x16x32_f16(al, Whi[i], acc, 0, 0, 0);
      }
    } else {
      // ---- k1 waves: stage B (ksteps 17..33; 32,33 come from s_seq) ----
#pragma unroll
      for (int g = 17; g < 34; ++g) {
#pragma unroll
        for (int p = 0; p < 2; ++p) {
          int idx = tid2 + 256 * p;
          int r = idx >> 5, kk = idx & 31;
          int k = 32 * g + kk;
          size_t bt = (size_t)(row0 + r) * TSTEPS + t;
          float v = (k < 1024) ? xs[bt * 1024 + k] : ss[bt * 64 + (k - 1024)];
          _Float16 h = (_Float16)v;
          int a = (g * 16 + r) * 40 + kk;
          Ahi[a] = h; Alo[a] = (_Float16)(v - (float)h);
        }
      }
    }
    __syncthreads();  // bar3

    if (kh == 1) {
      // ---- k1 waves: MFMA over ksteps 17..33, then publish partials ----
#pragma unroll
      for (int i = 0; i < 17; ++i) {
        int g = 17 + i;
        const _Float16* ap = Ahi + (g * 16 + l15) * 40 + 8 * lg;
        const _Float16* lp = Alo + (g * 16 + l15) * 40 + 8 * lg;
        f16x8 ah = *(const f16x8*)ap;
        f16x8 al = *(const f16x8*)lp;
        acc = __builtin_amdgcn_mfma_f32_16x16x32_f16(ah, Whi[i], acc, 0, 0, 0);
        acc = __builtin_amdgcn_mfma_f32_16x16x32_f16(ah, Wlo[i], acc, 0, 0, 0);
        acc = __builtin_amdgcn_mfma_f32_16x16x32_f16(al, Whi[i], acc, 0, 0, 0);
      }
#pragma unroll
      for (int i = 0; i < 4; ++i)
        red[(n * 16 + lg * 4 + i) * 17 + l15] = acc[i];
    }
    __syncthreads();  // bar4

    if (kh == 0) {
      // ---- epilogue: reduce + drive + tanh + leak + store x_{t+1} ----
#pragma unroll
      for (int i = 0; i < 4; ++i) {
        int r = lg * 4 + i;
        float z = acc[i] + red[(n * 16 + r) * 17 + l15] + bcol;
        if (s == 0) z += ust[r * 64 + n * 16 + l15];
        float xnew = 0.9f * xold[i] + 0.1f * tanhf(z);
        xold[i] = xnew;
        xs[((size_t)(row0 + r) * TSTEPS + (t + 1)) * 1024 + jcol] = xnew;
      }
    }
    __syncthreads();  // bar5 (drains stores before release)
    if (tid == 0)
      __hip_atomic_fetch_add(flag, 1u, __ATOMIC_RELEASE, __HIP_MEMORY_SCOPE_AGENT);
  }
}

// ---- readout: y[bt, :] = x_seq[bt, :] @ Wy^T + by  (f16 single precision) ----
__global__ __launch_bounds__(256, 2) void y_kernel(
    const float* __restrict__ xs, const float* __restrict__ Wy,
    const float* __restrict__ by, float* __restrict__ ys)
{
  __shared__ _Float16 Af[64][72];
  __shared__ _Float16 Bf[64][72];
  const int tid = threadIdx.x;
  const int lane = tid & 63;
  const int wave = tid >> 6;    // 0..3, each owns a 16-row slice
  const int l15 = lane & 15, lg = lane >> 4;
  const size_t bm = (size_t)blockIdx.x * 64;
  const int bn = blockIdx.y * 64;

  f32x4 acc[4];
#pragma unroll
  for (int q = 0; q < 4; ++q) acc[q] = (f32x4){0.f, 0.f, 0.f, 0.f};

  for (int kc = 0; kc < 16; ++kc) {
#pragma unroll
    for (int p = 0; p < 4; ++p) {
      int fi = tid + 256 * p;            // 0..1023
      int r = fi >> 4, kq = fi & 15;
      vf4 va = *(const vf4*)(xs + (bm + r) * 1024 + kc * 64 + kq * 4);
      f16x4 ha;
#pragma unroll
      for (int e = 0; e < 4; ++e) ha[e] = (_Float16)va[e];
      *(f16x4*)(&Af[r][kq * 4]) = ha;
      vf4 vb = *(const vf4*)(Wy + (size_t)(bn + r) * 1024 + kc * 64 + kq * 4);
      f16x4 hb;
#pragma unroll
      for (int e = 0; e < 4; ++e) hb[e] = (_Float16)vb[e];
      *(f16x4*)(&Bf[r][kq * 4]) = hb;
    }
    __syncthreads();
#pragma unroll
    for (int ks = 0; ks < 2; ++ks) {
      int k0 = ks * 32 + 8 * lg;
      f16x8 af = *(const f16x8*)(&Af[wave * 16 + l15][k0]);
#pragma unroll
      for (int nt = 0; nt < 4; ++nt) {
        f16x8 bf = *(const f16x8*)(&Bf[nt * 16 + l15][k0]);
        acc[nt] = __builtin_amdgcn_mfma_f32_16x16x32_f16(af, bf, acc[nt], 0, 0, 0);
      }
    }
    __syncthreads();
  }
#pragma unroll
  for (int nt = 0; nt < 4; ++nt) {
#pragma unroll
    for (int i = 0; i < 4; ++i) {
      size_t grow = bm + wave * 16 + lg * 4 + i;
      int gcol = bn + nt * 16 + l15;
      ys[grow * 256 + gcol] = acc[nt][i] + by[gcol];
    }
  }
}

extern "C" void kernel_launch(void* const* d_in, const int* in_sizes, int n_in,
                              void* d_out, int out_size, void* d_ws, size_t ws_size,
                              hipStream_t stream) {
  const float* x0 = (const float*)d_in[0];
  const float* ss = (const float*)d_in[1];
  const float* us = (const float*)d_in[2];
  const float* Bs = (const float*)d_in[3];
  const float* W  = (const float*)d_in[4];
  const float* bv = (const float*)d_in[5];
  const float* Wy = (const float*)d_in[6];
  const float* by = (const float*)d_in[7];
  float* xs = (float*)d_out;
  float* ys = xs + (size_t)256 * TSTEPS * DIMX;
  unsigned* flags = (unsigned*)d_ws;

  // zero the per-cluster flag counters every call (graph-capture-safe)
  hipMemsetAsync(d_ws, 0, 16 * 32 * sizeof(unsigned), stream);

  // allow >64KB dynamic LDS for the scan kernel (idempotent, host-side)
  (void)hipFuncSetAttribute(reinterpret_cast<const void*>(scan_kernel),
                            hipFuncAttributeMaxDynamicSharedMemorySize, SCAN_LDS);

  scan_kernel<<<dim3(256), dim3(512), SCAN_LDS, stream>>>(
      x0, ss, us, Bs, W, bv, xs, flags);
  y_kernel<<<dim3(1024, 4), dim3(256), 0, stream>>>(xs, Wy, by, ys);
}

// Round 2
// 2377.304 us; speedup vs baseline: 2.0130x; 2.0130x over previous
//
#include <hip/hip_runtime.h>
#include <hip/hip_fp16.h>

// RNN scan: x_{t+1} = 0.9 x_t + 0.1 tanh(W x_t + Bs s_t + pad(u_t) + b)
// 16 clusters x 16 WGs; W in registers (f16 hi/lo, 3-MFMA compensated).
// Sync redesign vs R1: x_{t+1} written via relaxed agent-scope atomic stores
// (sc1 write-through to MALL) so NO buffer_wbl2/buffer_inv fences are needed;
// per-wave relaxed flag increments (64 per cluster-step); 2 barriers/step.

#define DIMX 1024
#define TSTEPS 256

typedef _Float16 f16x8 __attribute__((ext_vector_type(8)));
typedef _Float16 f16x4 __attribute__((ext_vector_type(4)));
typedef float f32x4 __attribute__((ext_vector_type(4)));
typedef float vf4 __attribute__((ext_vector_type(4)));
typedef float vf2 __attribute__((ext_vector_type(2)));

// LDS layout (dynamic, 100096 B):
//  Ahi : [34][16][40] f16   43520 B  (row pad 40 f16 = 80 B -> 2-way-max banks)
//  Alo : [34][16][40] f16   43520 B  (offset 43520)
//  red : [64][17] f32        4352 B  (offset 87040)
//  ust : [2][16][68] f32     8704 B  (offset 91392, double-buffered by t&1)
#define SCAN_LDS 100096

__global__ __launch_bounds__(512, 2) void scan_kernel(
    const float* __restrict__ x0, const float* __restrict__ ss,
    const float* __restrict__ us, const float* __restrict__ Bsm,
    const float* __restrict__ Wm, const float* __restrict__ bv,
    float* __restrict__ xs, unsigned* __restrict__ flags)
{
  extern __shared__ char smem[];
  _Float16* Ahi = (_Float16*)smem;
  _Float16* Alo = (_Float16*)(smem + 43520);
  float* red = (float*)(smem + 87040);
  float* ust = (float*)(smem + 91392);

  const int tid  = threadIdx.x;
  const int lane = tid & 63;
  const int wave = tid >> 6;        // 0..7
  const int n    = wave & 3;        // N-tile (16 cols) within WG
  const int kh   = wave >> 2;       // K-half (ksteps 0..16 / 17..33)
  const int bid  = blockIdx.x;
  const int jb   = bid >> 3;
  const int c    = (bid & 7) + 8 * (jb >> 4);   // cluster 0..15 (XCD-local hint)
  const int s    = jb & 15;                     // WG within cluster
  const int row0 = c * 16;                      // batch rows of cluster
  const int col0 = s * 64;                      // output cols of WG
  unsigned* flag = flags + c * 32;              // 128B-padded counter

  const int l15 = lane & 15;
  const int lg  = lane >> 4;                    // 0..3
  const int jcol = col0 + n * 16 + l15;         // this lane's output column

  // ---- preload W slice (f16 hi/lo) into registers: 17 ksteps x 8 elems ----
  f16x8 Whi[17], Wlo[17];
#pragma unroll
  for (int i = 0; i < 17; ++i) {
    int g = kh * 17 + i;
    int kb = 32 * g + 8 * lg;
    vf4 v0, v1;
    if (g < 32) {
      const float* p = Wm + (size_t)jcol * 1024 + kb;
      v0 = *(const vf4*)p; v1 = *(const vf4*)(p + 4);
    } else {
      const float* p = Bsm + (size_t)jcol * 64 + (kb - 1024);
      v0 = *(const vf4*)p; v1 = *(const vf4*)(p + 4);
    }
#pragma unroll
    for (int e = 0; e < 4; ++e) {
      float va = v0[e]; _Float16 h = (_Float16)va;
      Whi[i][e] = h; Wlo[i][e] = (_Float16)(va - (float)h);
      float vb = v1[e]; _Float16 h2 = (_Float16)vb;
      Whi[i][e + 4] = h2; Wlo[i][e + 4] = (_Float16)(vb - (float)h2);
    }
  }

  const float bcol = bv[jcol];

  // x_old tile in kh==0 waves' registers (C/D layout: col=l15, row=lg*4+i)
  f32x4 xold = {0.f, 0.f, 0.f, 0.f};
  if (kh == 0) {
#pragma unroll
    for (int i = 0; i < 4; ++i)
      xold[i] = x0[(size_t)(row0 + lg * 4 + i) * 1024 + jcol];
  }

  // ---- x_seq[:,0,:] = x0 (own tile; nobody reads it during the scan) ----
  {
    int i0 = tid * 2; int r = i0 >> 6, cc = i0 & 63;
    *(vf2*)&xs[((size_t)(row0 + r) * TSTEPS) * 1024 + col0 + cc] =
        *(const vf2*)&x0[(size_t)(row0 + r) * 1024 + col0 + cc];
  }

  const int srow = tid >> 5;         // staging row 0..15
  const int spos = tid & 31;         // 32 threads per row
  const int skk  = (tid & 7) * 4;    // f16 k-offset within kstep

  for (int t = 0; t < TSTEPS - 1; ++t) {
    // ---- wait for all 64 producer-waves of x_t (relaxed poll, no inv) ----
    if (t > 0) {
      unsigned tgt = 64u * (unsigned)t;
      while (__hip_atomic_load(flag, __ATOMIC_RELAXED, __HIP_MEMORY_SCOPE_AGENT) < tgt)
        __builtin_amdgcn_s_sleep(1);
    }
    asm volatile("" ::: "memory");   // compiler barrier: no hoisting loads above poll

    // ---- stage x_t (vectorized): 16 rows x 1024, float4 per thread x8 ----
    {
      const float* rb = (t == 0)
          ? (x0 + (size_t)(row0 + srow) * 1024)
          : (xs + ((size_t)(row0 + srow) * TSTEPS + t) * 1024);
#pragma unroll
      for (int j = 0; j < 8; ++j) {
        int k = spos * 4 + j * 128;
        vf4 v = *(const vf4*)(rb + k);
        int g = (spos >> 3) + 4 * j;
        f16x4 h, l;
#pragma unroll
        for (int e = 0; e < 4; ++e) {
          float va = v[e]; _Float16 hh = (_Float16)va;
          h[e] = hh; l[e] = (_Float16)(va - (float)hh);
        }
        int a = (g * 16 + srow) * 40 + skk;
        *(f16x4*)(Ahi + a) = h;
        *(f16x4*)(Alo + a) = l;
      }
      // s_t -> ksteps 32,33
      int i0 = tid * 2; int r = i0 >> 6, cc = i0 & 63;
      vf2 v = *(const vf2*)(ss + ((size_t)(row0 + r) * TSTEPS + t) * 64 + cc);
      int g = 32 + (cc >> 5), kk = cc & 31;
      int a = (g * 16 + r) * 40 + kk;
#pragma unroll
      for (int e = 0; e < 2; ++e) {
        float va = v[e]; _Float16 hh = (_Float16)va;
        Ahi[a + e] = hh; Alo[a + e] = (_Float16)(va - (float)hh);
      }
      // u_t (only cols 0..63 get the u drive -> cluster-WG s==0)
      if (s == 0 && tid < 256) {
        int ur = tid >> 4, uc = (tid & 15) * 4;
        *(vf4*)&ust[(t & 1) * (16 * 68) + ur * 68 + uc] =
            *(const vf4*)(us + ((size_t)(row0 + ur) * TSTEPS + t) * 64 + uc);
      }
    }
    __syncthreads();  // barA: tile staged

    // ---- MFMA: both K-halves in parallel; 3 independent acc chains ----
    f32x4 a0 = {0.f,0.f,0.f,0.f}, a1 = {0.f,0.f,0.f,0.f}, a2 = {0.f,0.f,0.f,0.f};
#pragma unroll
    for (int i = 0; i < 17; ++i) {
      int g = kh * 17 + i;
      const int ab = (g * 16 + l15) * 40 + 8 * lg;
      f16x8 ah = *(const f16x8*)(Ahi + ab);
      f16x8 al = *(const f16x8*)(Alo + ab);
      a0 = __builtin_amdgcn_mfma_f32_16x16x32_f16(ah, Whi[i], a0, 0, 0, 0);
      a1 = __builtin_amdgcn_mfma_f32_16x16x32_f16(ah, Wlo[i], a1, 0, 0, 0);
      a2 = __builtin_amdgcn_mfma_f32_16x16x32_f16(al, Whi[i], a2, 0, 0, 0);
    }
    if (kh == 1) {
#pragma unroll
      for (int i = 0; i < 4; ++i)
        red[(n * 16 + lg * 4 + i) * 17 + l15] = a0[i] + a1[i] + a2[i];
    }
    __syncthreads();  // barB: partials published

    if (kh == 0) {
      // ---- epilogue: reduce + drive + tanh + leak + write-through store ----
#pragma unroll
      for (int i = 0; i < 4; ++i) {
        int r = lg * 4 + i;
        float z = a0[i] + a1[i] + a2[i] + red[(n * 16 + r) * 17 + l15] + bcol;
        if (s == 0) z += ust[(t & 1) * (16 * 68) + r * 68 + (n * 16 + l15)];
        float xnew = 0.9f * xold[i] + 0.1f * tanhf(z);
        xold[i] = xnew;
        __hip_atomic_store(&xs[((size_t)(row0 + r) * TSTEPS + (t + 1)) * 1024 + jcol],
                           xnew, __ATOMIC_RELAXED, __HIP_MEMORY_SCOPE_AGENT);
      }
      asm volatile("s_waitcnt vmcnt(0)" ::: "memory");  // stores visible at MALL
      if (lane == 0)
        __hip_atomic_fetch_add(flag, 1u, __ATOMIC_RELAXED, __HIP_MEMORY_SCOPE_AGENT);
    }
  }
}

// ---- readout: y[bt, :] = x_seq[bt, :] @ Wy^T + by  (f16 single precision) ----
__global__ __launch_bounds__(256, 2) void y_kernel(
    const float* __restrict__ xs, const float* __restrict__ Wy,
    const float* __restrict__ by, float* __restrict__ ys)
{
  __shared__ _Float16 Af[64][72];
  __shared__ _Float16 Bf[64][72];
  const int tid = threadIdx.x;
  const int lane = tid & 63;
  const int wave = tid >> 6;    // 0..3, each owns a 16-row slice
  const int l15 = lane & 15, lg = lane >> 4;
  const size_t bm = (size_t)blockIdx.x * 64;
  const int bn = blockIdx.y * 64;

  f32x4 acc[4];
#pragma unroll
  for (int q = 0; q < 4; ++q) acc[q] = (f32x4){0.f, 0.f, 0.f, 0.f};

  for (int kc = 0; kc < 16; ++kc) {
#pragma unroll
    for (int p = 0; p < 4; ++p) {
      int fi = tid + 256 * p;            // 0..1023
      int r = fi >> 4, kq = fi & 15;
      vf4 va = *(const vf4*)(xs + (bm + r) * 1024 + kc * 64 + kq * 4);
      f16x4 ha;
#pragma unroll
      for (int e = 0; e < 4; ++e) ha[e] = (_Float16)va[e];
      *(f16x4*)(&Af[r][kq * 4]) = ha;
      vf4 vb = *(const vf4*)(Wy + (size_t)(bn + r) * 1024 + kc * 64 + kq * 4);
      f16x4 hb;
#pragma unroll
      for (int e = 0; e < 4; ++e) hb[e] = (_Float16)vb[e];
      *(f16x4*)(&Bf[r][kq * 4]) = hb;
    }
    __syncthreads();
#pragma unroll
    for (int ks = 0; ks < 2; ++ks) {
      int k0 = ks * 32 + 8 * lg;
      f16x8 af = *(const f16x8*)(&Af[wave * 16 + l15][k0]);
#pragma unroll
      for (int nt = 0; nt < 4; ++nt) {
        f16x8 bf = *(const f16x8*)(&Bf[nt * 16 + l15][k0]);
        acc[nt] = __builtin_amdgcn_mfma_f32_16x16x32_f16(af, bf, acc[nt], 0, 0, 0);
      }
    }
    __syncthreads();
  }
#pragma unroll
  for (int nt = 0; nt < 4; ++nt) {
#pragma unroll
    for (int i = 0; i < 4; ++i) {
      size_t grow = bm + wave * 16 + lg * 4 + i;
      int gcol = bn + nt * 16 + l15;
      ys[grow * 256 + gcol] = acc[nt][i] + by[gcol];
    }
  }
}

extern "C" void kernel_launch(void* const* d_in, const int* in_sizes, int n_in,
                              void* d_out, int out_size, void* d_ws, size_t ws_size,
                              hipStream_t stream) {
  const float* x0 = (const float*)d_in[0];
  const float* ss = (const float*)d_in[1];
  const float* us = (const float*)d_in[2];
  const float* Bs = (const float*)d_in[3];
  const float* W  = (const float*)d_in[4];
  const float* bv = (const float*)d_in[5];
  const float* Wy = (const float*)d_in[6];
  const float* by = (const float*)d_in[7];
  float* xs = (float*)d_out;
  float* ys = xs + (size_t)256 * TSTEPS * DIMX;
  unsigned* flags = (unsigned*)d_ws;

  // zero the per-cluster flag counters every call (graph-capture-safe)
  hipMemsetAsync(d_ws, 0, 16 * 32 * sizeof(unsigned), stream);

  // allow >64KB dynamic LDS for the scan kernel
  (void)hipFuncSetAttribute(reinterpret_cast<const void*>(scan_kernel),
                            hipFuncAttributeMaxDynamicSharedMemorySize, SCAN_LDS);

  scan_kernel<<<dim3(256), dim3(512), SCAN_LDS, stream>>>(
      x0, ss, us, Bs, W, bv, xs, flags);
  y_kernel<<<dim3(1024, 4), dim3(256), 0, stream>>>(xs, Wy, by, ys);
}